// Round 1
// 68.260 us; speedup vs baseline: 1.0582x; 1.0582x over previous
//
#include <hip/hip_runtime.h>

// FSQ: z (4,16,256,64) fp32, bins (64,256) fp32 (uniform linspace(-1,1,256) per row).
// Outputs flat fp32: [loss(1), z_q(1048576), bin_indices_as_float(1048576)]
// loss = 2 * mean((z - zq)^2)   (commitment + BETA*codebook, BETA=1, identical forward)
//
// R1: 4 elems/thread with k*BLOCK stride (d = tid&63 is per-thread constant ->
//     one bins row per thread, L1-friendly; all accesses stay dword-coalesced),
//     1024 blocks (was 4096), single-wave reduce (no LDS/sync, 1024 partials).

#define N_ELEM (4 * 16 * 256 * 64) // 1048576
#define D_LAT 64
#define NBINS 256
#define BLOCK 256
#define VPT 4
#define CHUNK (BLOCK * VPT)   // 1024 elements per block
#define GRID (N_ELEM / CHUNK) // 1024

__global__ __launch_bounds__(BLOCK) void fsq_main(const float* __restrict__ z,
                                                  const float* __restrict__ bins,
                                                  float* __restrict__ out,
                                                  float* __restrict__ partial) {
    const int tid = threadIdx.x;
    const int base = blockIdx.x * CHUNK + tid;
    // CHUNK and BLOCK are multiples of 64, so d = (base + k*BLOCK) & 63 == tid & 63:
    // each thread reads from exactly one 1KB bins row across all VPT elements.
    const float* __restrict__ brow = bins + (tid & (D_LAT - 1)) * NBINS;

    float s = 0.0f;
#pragma unroll
    for (int k = 0; k < VPT; ++k) {
        const int i = base + k * BLOCK;
        const float v = z[i];

        // Candidate nearest-bin index via uniform-spacing formula, clamped.
        float t = (v + 1.0f) * 127.5f;
        int j = (int)floorf(t + 0.5f);
        j = min(max(j, 0), NBINS - 1);

        // Refine with actual bin values; tie-break to LOWEST index (argmin semantics).
        int best = j;
        float bv = brow[j];
        float bd = fabsf(v - bv);
        if (j > 0) {
            float b0 = brow[j - 1];
            float d0 = fabsf(v - b0);
            if (d0 <= bd) { best = j - 1; bv = b0; bd = d0; } // <= : lower index wins tie
        }
        if (j + 1 < NBINS) {
            float b1 = brow[j + 1];
            float d1 = fabsf(v - b1);
            if (d1 < bd) { best = j + 1; bv = b1; bd = d1; } // strict < : lower index wins tie
        }

        out[1 + i] = bv;
        out[1 + N_ELEM + i] = (float)best;

        float diff = v - bv;
        s = fmaf(diff, diff, s);
    }

    // wave reduce, then 4-wave LDS combine -> one partial per block
#pragma unroll
    for (int off = 32; off > 0; off >>= 1) s += __shfl_down(s, off, 64);

    __shared__ float lds[BLOCK / 64];
    const int lane = tid & 63;
    const int wave = tid >> 6;
    if (lane == 0) lds[wave] = s;
    __syncthreads();
    if (tid == 0) partial[blockIdx.x] = lds[0] + lds[1] + lds[2] + lds[3];
}

__global__ __launch_bounds__(64) void fsq_reduce(const float* __restrict__ partial,
                                                 float* __restrict__ out) {
    // single wave: 16 coalesced strided loads, butterfly reduce, no LDS/sync
    float s = 0.0f;
#pragma unroll
    for (int k = 0; k < GRID / 64; ++k) s += partial[threadIdx.x + k * 64];
#pragma unroll
    for (int off = 32; off > 0; off >>= 1) s += __shfl_down(s, off, 64);
    if (threadIdx.x == 0) out[0] = 2.0f * s / (float)N_ELEM; // (1 + BETA) * mean
}

extern "C" void kernel_launch(void* const* d_in, const int* in_sizes, int n_in,
                              void* d_out, int out_size, void* d_ws, size_t ws_size,
                              hipStream_t stream) {
    const float* z = (const float*)d_in[0];
    const float* bins = (const float*)d_in[1];
    float* out = (float*)d_out;
    float* partial = (float*)d_ws; // 1024 floats, fully written before read

    fsq_main<<<GRID, BLOCK, 0, stream>>>(z, bins, out, partial);
    fsq_reduce<<<1, 64, 0, stream>>>(partial, out);
}